// Round 8
// baseline (656.530 us; speedup 1.0000x reference)
//
#include <hip/hip_runtime.h>
#include <hip/hip_bf16.h>
#include <math.h>

#define B_    8
#define SEQ_  4096
#define CIN_  7
#define DM_   512
#define NL_   4
#define PL_   16
#define NP_   256
#define NS_   16
#define DC_   4
#define DI_   1024
#define DTR_  32
#define CD_   64
#define PRED_ 96
#define TOK_  (B_*NP_)   // 2048
#define EPS_  1e-5f
#define CL_   16         // scan chunk length
#define NCH_  (NP_/CL_)  // 16 chunks

typedef unsigned short u16;
typedef __attribute__((ext_vector_type(8))) short short8;
typedef __attribute__((ext_vector_type(4))) float floatx4;

__device__ __forceinline__ float silu_f(float x){ return x / (1.f + __expf(-x)); }
__device__ __forceinline__ float softplus_f(float x){ return x > 20.f ? x : log1pf(__expf(x)); }
__device__ __forceinline__ u16 f2bf(float f){
  union { __hip_bfloat16 h; u16 u; } cv; cv.h = __float2bfloat16(f); return cv.u;
}
#define GLDS16(g, l) __builtin_amdgcn_global_load_lds( \
    (const __attribute__((address_space(1))) void*)(g), \
    (__attribute__((address_space(3))) void*)(l), 16, 0, 0)

// ---------------- LN over CIN=7 -> bf16 patch rows [2048][128] (zero-padded 112..127) ----------------
__global__ void ln7_kernel(const float* __restrict__ x, const float* __restrict__ g,
                           const float* __restrict__ b, u16* __restrict__ xpb){
  int i = blockIdx.x*256 + threadIdx.x; // over B*SEQ
  if (i >= B_*SEQ_) return;
  float v[CIN_]; float m = 0.f;
  #pragma unroll
  for (int c=0;c<CIN_;c++){ v[c]=x[i*CIN_+c]; m+=v[c]; }
  m *= (1.f/CIN_);
  float var = 0.f;
  #pragma unroll
  for (int c=0;c<CIN_;c++){ float d=v[c]-m; var+=d*d; }
  var *= (1.f/CIN_);
  float r = rsqrtf(var + EPS_);
  int bn = i >> 4, p = i & 15;            // token, pos-in-patch
  u16* row = xpb + (size_t)bn*128;
  #pragma unroll
  for (int c=0;c<CIN_;c++) row[c*16+p] = f2bf((v[c]-m)*r*g[c]+b[c]);
  row[112+p] = 0;
}

// ---------------- LN over DM=512, wave-per-token, fp32+bf16 out ----------------
__global__ __launch_bounds__(256) void ln512_kernel(const float* __restrict__ in,
    const float* __restrict__ g, const float* __restrict__ b,
    float* __restrict__ out, u16* __restrict__ outb){
  int tid = threadIdx.x;
  int wv = tid>>6, lane = tid&63;
  int t = blockIdx.x*4 + wv;
  const float4* row = (const float4*)(in + (size_t)t*DM_);
  float4 v0 = row[lane], v1 = row[64+lane];
  float s = v0.x+v0.y+v0.z+v0.w + v1.x+v1.y+v1.z+v1.w;
  #pragma unroll
  for (int o=1;o<64;o<<=1) s += __shfl_xor(s,o);
  float m = s*(1.f/DM_);
  float d0x=v0.x-m,d0y=v0.y-m,d0z=v0.z-m,d0w=v0.w-m;
  float d1x=v1.x-m,d1y=v1.y-m,d1z=v1.z-m,d1w=v1.w-m;
  float q = d0x*d0x+d0y*d0y+d0z*d0z+d0w*d0w + d1x*d1x+d1y*d1y+d1z*d1z+d1w*d1w;
  #pragma unroll
  for (int o=1;o<64;o<<=1) q += __shfl_xor(q,o);
  float r = rsqrtf(q*(1.f/DM_) + EPS_);
  float4 g0 = ((const float4*)g)[lane], g1 = ((const float4*)g)[64+lane];
  float4 b0 = ((const float4*)b)[lane], b1 = ((const float4*)b)[64+lane];
  float4 o0 = { d0x*r*g0.x+b0.x, d0y*r*g0.y+b0.y, d0z*r*g0.z+b0.z, d0w*r*g0.w+b0.w };
  float4 o1 = { d1x*r*g1.x+b1.x, d1y*r*g1.y+b1.y, d1z*r*g1.z+b1.z, d1w*r*g1.w+b1.w };
  ((float4*)(out + (size_t)t*DM_))[lane]    = o0;
  ((float4*)(out + (size_t)t*DM_))[64+lane] = o1;
  ushort4 p0 = { f2bf(o0.x), f2bf(o0.y), f2bf(o0.z), f2bf(o0.w) };
  ushort4 p1 = { f2bf(o1.x), f2bf(o1.y), f2bf(o1.z), f2bf(o1.w) };
  ((ushort4*)(outb + (size_t)t*DM_))[lane]    = p0;
  ((ushort4*)(outb + (size_t)t*DM_))[64+lane] = p1;
}

// ---------------- bf16 MFMA NT GEMM: C[M,N](f32) = A[M,K]*B[N,K]^T (+bias) ----------------
template<int BM, int BN, bool ACC, bool BIAS>
__global__ __launch_bounds__(256) void gemm_bf16(const u16* __restrict__ A,
    const u16* __restrict__ Bw, float* __restrict__ C, const float* __restrict__ bias,
    int K, int lda, int ldb, int ldc){
  constexpr int MI = BM/32, NI = BN/32;
  __shared__ __align__(16) u16 As[BM*64];
  __shared__ __align__(16) u16 Bs[BN*64];
  int tid = threadIdx.x;
  int wave = __builtin_amdgcn_readfirstlane(tid>>6);
  int lane = tid&63;
  int wm = wave>>1, wn = wave&1;
  int quad = lane>>4, l16 = lane&15;
  int bm = blockIdx.y*BM, bn = blockIdx.x*BN;
  int r8 = lane>>3, sseg = lane&7;
  int gseg = sseg ^ r8;                  // global k-seg this lane fetches
  floatx4 acc[MI][NI] = {};
  for (int k0 = 0; k0 < K; k0 += 64){
    #pragma unroll
    for (int r = 0; r < BM/32; r++){
      int rowb = (r*4 + wave)*8;
      const u16* gp = A + (size_t)(bm + rowb + r8)*lda + k0 + gseg*8;
      GLDS16(gp, &As[rowb*64]);
    }
    #pragma unroll
    for (int r = 0; r < BN/32; r++){
      int rowb = (r*4 + wave)*8;
      const u16* gp = Bw + (size_t)(bn + rowb + r8)*ldb + k0 + gseg*8;
      GLDS16(gp, &Bs[rowb*64]);
    }
    __syncthreads();
    #pragma unroll
    for (int kh = 0; kh < 2; kh++){
      short8 af[MI], bfr[NI];
      #pragma unroll
      for (int i = 0; i < MI; i++){
        int row = wm*(BM/2)+i*16+l16;
        af[i] = *(short8*)&As[row*64 + (((kh*4+quad)^(row&7))*8)];
      }
      #pragma unroll
      for (int j = 0; j < NI; j++){
        int row = wn*(BN/2)+j*16+l16;
        bfr[j] = *(short8*)&Bs[row*64 + (((kh*4+quad)^(row&7))*8)];
      }
      #pragma unroll
      for (int i = 0; i < MI; i++)
        #pragma unroll
        for (int j = 0; j < NI; j++)
          acc[i][j] = __builtin_amdgcn_mfma_f32_16x16x32_bf16(af[i], bfr[j], acc[i][j], 0, 0, 0);
    }
    __syncthreads();
  }
  #pragma unroll
  for (int i = 0; i < MI; i++){
    #pragma unroll
    for (int j = 0; j < NI; j++){
      #pragma unroll
      for (int r = 0; r < 4; r++){
        int m  = bm + wm*(BM/2) + i*16 + quad*4 + r;
        int nn = bn + wn*(BN/2) + j*16 + l16;
        float v = acc[i][j][r];
        if (ACC) C[(size_t)m*ldc+nn] += v;
        else     C[(size_t)m*ldc+nn]  = BIAS ? v + bias[nn] : v;
      }
    }
  }
}

// ---------------- dbl split-K partial GEMM: part[kc][64t][64e] over K=256 chunk ----------------
__global__ __launch_bounds__(256) void dblpart_kernel(const u16* __restrict__ A,
    const u16* __restrict__ Bw, float* __restrict__ part){
  __shared__ __align__(16) u16 As[64*64];
  __shared__ __align__(16) u16 Bs[64*64];
  int tid = threadIdx.x;
  int wave = __builtin_amdgcn_readfirstlane(tid>>6);
  int lane = tid&63;
  int wm = wave>>1, wn = wave&1;
  int quad = lane>>4, l16 = lane&15;
  int bm = blockIdx.x*64;
  int kc = blockIdx.y;                 // 0..3, K chunk of 256
  int r8 = lane>>3, sseg = lane&7;
  int gseg = sseg ^ r8;
  floatx4 acc[2][2] = {};
  for (int k0 = kc*256; k0 < kc*256 + 256; k0 += 64){
    #pragma unroll
    for (int r = 0; r < 2; r++){
      int rowb = (r*4 + wave)*8;
      GLDS16(A  + (size_t)(bm + rowb + r8)*DI_ + k0 + gseg*8, &As[rowb*64]);
      GLDS16(Bw + (size_t)(     rowb + r8)*DI_ + k0 + gseg*8, &Bs[rowb*64]);
    }
    __syncthreads();
    #pragma unroll
    for (int kh = 0; kh < 2; kh++){
      short8 af[2], bfr[2];
      #pragma unroll
      for (int i = 0; i < 2; i++){
        int row = wm*32+i*16+l16;
        af[i] = *(short8*)&As[row*64 + (((kh*4+quad)^(row&7))*8)];
      }
      #pragma unroll
      for (int j = 0; j < 2; j++){
        int row = wn*32+j*16+l16;
        bfr[j] = *(short8*)&Bs[row*64 + (((kh*4+quad)^(row&7))*8)];
      }
      #pragma unroll
      for (int i = 0; i < 2; i++)
        #pragma unroll
        for (int j = 0; j < 2; j++)
          acc[i][j] = __builtin_amdgcn_mfma_f32_16x16x32_bf16(af[i], bfr[j], acc[i][j], 0, 0, 0);
    }
    __syncthreads();
  }
  float* dst = part + (size_t)kc*TOK_*64;
  #pragma unroll
  for (int i = 0; i < 2; i++)
    #pragma unroll
    for (int j = 0; j < 2; j++)
      #pragma unroll
      for (int r = 0; r < 4; r++){
        int m  = bm + wm*32 + i*16 + quad*4 + r;
        int nn = wn*32 + j*16 + l16;
        dst[(size_t)m*64+nn] = acc[i][j][r];
      }
}

// ---------------- causal depthwise conv (DC=4) + bias + silu -> xc fp32 + xcb bf16 ----------------
__global__ void conv_silu_kernel(const float* __restrict__ xz, const float* __restrict__ cW,
                                 const float* __restrict__ cb, float* __restrict__ xc,
                                 u16* __restrict__ xcb){
  int idx = blockIdx.x*256 + threadIdx.x;   // over TOK*DI/4
  if (idx >= TOK_*DI_/4) return;
  int c4 = idx & (DI_/4 - 1); int t = idx >> 8;
  int l = t & (NP_-1);
  int c = c4*4;
  float4 acc = *(const float4*)&cb[c];
  float wa[4], wb[4], wc[4], wd[4];
  *(float4*)wa = *(const float4*)&cW[(c+0)*DC_];
  *(float4*)wb = *(const float4*)&cW[(c+1)*DC_];
  *(float4*)wc = *(const float4*)&cW[(c+2)*DC_];
  *(float4*)wd = *(const float4*)&cW[(c+3)*DC_];
  const float* base = xz + (size_t)t*(2*DI_) + c;
  #pragma unroll
  for (int k = 0; k < DC_; k++){
    if (l - 3 + k >= 0){
      float4 xv = *(const float4*)(base + (k-3)*(2*DI_));
      acc.x += xv.x*wa[k];
      acc.y += xv.y*wb[k];
      acc.z += xv.z*wc[k];
      acc.w += xv.w*wd[k];
    }
  }
  acc.x = silu_f(acc.x); acc.y = silu_f(acc.y);
  acc.z = silu_f(acc.z); acc.w = silu_f(acc.w);
  *(float4*)&xc[(size_t)t*DI_ + c] = acc;
  ushort4 pb = { f2bf(acc.x), f2bf(acc.y), f2bf(acc.z), f2bf(acc.w) };
  *(ushort4*)&xcb[(size_t)t*DI_ + c] = pb;
}

// ---------------- delta v2: sum dbl partials -> dbl, then delta = softplus(dt@W_dt^T+b) ----------------
__global__ __launch_bounds__(256) void delta_kernel(const float* __restrict__ part,
    const float* __restrict__ wdtT, const float* __restrict__ bdt,
    float* __restrict__ dbl, float* __restrict__ delta){
  __shared__ float sdbl[16][64];
  int tid = threadIdx.x;
  int t0 = blockIdx.x*16;
  // sum 4 k-partials: 1024 elems, 4 per thread
  #pragma unroll
  for (int i = tid; i < 16*64; i += 256){
    int t = i >> 6, e = i & 63;
    size_t o = (size_t)(t0 + t)*64 + e;
    float s = part[o] + part[(size_t)TOK_*64 + o]
            + part[(size_t)2*TOK_*64 + o] + part[(size_t)3*TOK_*64 + o];
    sdbl[t][e] = s;
    dbl[o] = s;
  }
  __syncthreads();
  #pragma unroll
  for (int dc = 0; dc < 4; dc++){
    int d = dc*256 + tid;
    float wr[DTR_];
    #pragma unroll
    for (int r = 0; r < DTR_; r++) wr[r] = wdtT[(size_t)r*DI_ + d];
    float bb = bdt[d];
    #pragma unroll
    for (int t = 0; t < 16; t++){
      float acc = bb;
      #pragma unroll
      for (int r = 0; r < DTR_; r++) acc += sdbl[t][r]*wr[r];
      delta[(size_t)(t0 + t)*DI_ + d] = softplus_f(acc);
    }
  }
}

// ---------------- chunked selective scan, d-per-lane ----------------
__global__ __launch_bounds__(256) void scan_part_kernel(const float* __restrict__ delta,
    const float* __restrict__ xc, const float* __restrict__ dbl,
    const float* __restrict__ Alog, float* __restrict__ hend, float* __restrict__ aprod){
  __shared__ float sBC[CL_][32];
  int tid = threadIdx.x;
  int d = blockIdx.x*256 + tid;
  int bych = blockIdx.y;               // b*NCH + ch
  int b = bych >> 4, ch = bych & (NCH_-1);
  int base = b*NP_ + ch*CL_;
  for (int i = tid; i < CL_*32; i += 256){
    int t = i >> 5, c = i & 31;
    sBC[t][c] = dbl[(size_t)(base+t)*64 + 32 + c];
  }
  float A[NS_], h[NS_], pr[NS_];
  #pragma unroll
  for (int k = 0; k < NS_; k++){
    A[k] = -__expf(Alog[(size_t)d*NS_ + k]);
    h[k] = 0.f; pr[k] = 1.f;
  }
  __syncthreads();
  #pragma unroll
  for (int t = 0; t < CL_; t++){
    int row = base + t;
    float de = delta[(size_t)row*DI_ + d];
    float xv = xc[(size_t)row*DI_ + d];
    float cde = de*xv;
    #pragma unroll
    for (int k = 0; k < NS_; k++){
      float a = __expf(de*A[k]);
      h[k] = a*h[k] + cde*sBC[t][k];
      pr[k] *= a;
    }
  }
  size_t o = ((size_t)bych*DI_ + d)*NS_;
  #pragma unroll
  for (int k = 0; k < NS_; k++){ hend[o+k] = h[k]; aprod[o+k] = pr[k]; }
}

__global__ __launch_bounds__(256) void scan_fix_kernel(const float* __restrict__ aprod,
    float* __restrict__ hend){
  int id = blockIdx.x*256 + threadIdx.x;  // over B*DI*NS = 131072
  int nd = id & (DI_*NS_ - 1);
  int b  = id >> 14;
  float h = 0.f;
  #pragma unroll
  for (int ch = 0; ch < NCH_; ch++){
    size_t idx = (size_t)(b*NCH_ + ch)*(DI_*NS_) + nd;
    float ap = aprod[idx];
    float he = hend[idx];
    hend[idx] = h;
    h = ap*h + he;
  }
}

__global__ __launch_bounds__(256) void scan_final_kernel(const float* __restrict__ delta,
    const float* __restrict__ xc, const float* __restrict__ dbl,
    const float* __restrict__ xz, const float* __restrict__ Dv,
    const float* __restrict__ Alog, const float* __restrict__ hin,
    u16* __restrict__ yb){
  __shared__ float sBC[CL_][32];
  int tid = threadIdx.x;
  int d = blockIdx.x*256 + tid;
  int bych = blockIdx.y;
  int b = bych >> 4, ch = bych & (NCH_-1);
  int base = b*NP_ + ch*CL_;
  for (int i = tid; i < CL_*32; i += 256){
    int t = i >> 5, c = i & 31;
    sBC[t][c] = dbl[(size_t)(base+t)*64 + 32 + c];
  }
  float A[NS_], h[NS_];
  size_t o = ((size_t)bych*DI_ + d)*NS_;
  #pragma unroll
  for (int k = 0; k < NS_; k++){
    A[k] = -__expf(Alog[(size_t)d*NS_ + k]);
    h[k] = hin[o + k];
  }
  float Dvd = Dv[d];
  __syncthreads();
  #pragma unroll
  for (int t = 0; t < CL_; t++){
    int row = base + t;
    float de = delta[(size_t)row*DI_ + d];
    float xv = xc[(size_t)row*DI_ + d];
    float zz = xz[(size_t)row*(2*DI_) + DI_ + d];
    float cde = de*xv;
    float p = 0.f;
    #pragma unroll
    for (int k = 0; k < NS_; k++){
      float a = __expf(de*A[k]);
      h[k] = a*h[k] + cde*sBC[t][k];
      p += h[k]*sBC[t][16+k];
    }
    yb[(size_t)row*DI_ + d] = f2bf((p + xv*Dvd) * silu_f(zz));
  }
}

// ---------------- head GEMM1: wave-per-n, grid (32 nb, 64 kc), KLEN=2048 ----------------
__global__ __launch_bounds__(256) void head1_kernel(const float* __restrict__ u,
    const float* __restrict__ hW1, float* __restrict__ partial){
  const int KTOT = DM_*NP_;        // 131072
  int nb = blockIdx.x;             // 0..31 (4 n per block, wave-per-n)
  int kc = blockIdx.y;             // 0..63
  int tid = threadIdx.x;
  int lane = tid & 63, wv = tid >> 6;
  int n = nb*4 + wv;
  const float* wrow = hW1 + (size_t)n*KTOT;
  float acc[8] = {};
  int kb = kc*2048 + lane*4;
  #pragma unroll
  for (int it = 0; it < 8; it++){
    int k = kb + it*256;
    float4 w4 = *(const float4*)&wrow[k];
    #pragma unroll
    for (int m = 0; m < 8; m++){
      float4 u4 = *(const float4*)&u[(size_t)m*KTOT + k];
      acc[m] += u4.x*w4.x + u4.y*w4.y + u4.z*w4.z + u4.w*w4.w;
    }
  }
  #pragma unroll
  for (int m = 0; m < 8; m++){
    float v = acc[m];
    v += __shfl_xor(v,1); v += __shfl_xor(v,2); v += __shfl_xor(v,4);
    v += __shfl_xor(v,8); v += __shfl_xor(v,16); v += __shfl_xor(v,32);
    acc[m] = v;
  }
  if (lane == 0){
    float* dst = partial + ((size_t)kc*128 + n)*8;
    #pragma unroll
    for (int m = 0; m < 8; m++) dst[m] = acc[m];
  }
}

__global__ void head_combine_kernel(const float* __restrict__ partial,
    const float* __restrict__ hb1, float* __restrict__ t1){
  int idx = blockIdx.x*256 + threadIdx.x;  // n*8+m, 1024 total
  if (idx >= 128*8) return;
  int n = idx >> 3, m = idx & 7;
  float s = hb1[n];
  for (int kc = 0; kc < 64; kc++) s += partial[((size_t)kc*128 + n)*8 + m];
  float ge = 0.5f*s*(1.f + erff(s*0.70710678118f));
  t1[m*128 + n] = ge;
}

__global__ void head2_kernel(const float* __restrict__ t1, const float* __restrict__ hW2,
                             const float* __restrict__ hb2, float* __restrict__ out){
  int idx = blockIdx.x*128 + threadIdx.x;  // 8*96
  if (idx >= B_*PRED_) return;
  int m = idx / PRED_, q = idx % PRED_;
  float s = hb2[q];
  #pragma unroll 16
  for (int k = 0; k < 2*CD_; k++) s += t1[m*128 + k]*hW2[q*128 + k];
  out[idx] = s;
}

// ---------------- prep: vectorized bf16 conversions + transposes ----------------
__global__ __launch_bounds__(256) void prep_kernel(const float* __restrict__ W_dt,
    const float* __restrict__ W_x, const float* __restrict__ W_in,
    const float* __restrict__ W_out, const float* __restrict__ peW,
    float* __restrict__ wdtT, u16* __restrict__ wxB,
    u16* __restrict__ WinB, u16* __restrict__ WoutB, u16* __restrict__ peWb){
  int idx = blockIdx.x*256 + threadIdx.x;   // 1,048,576 threads
  {
    float4 v = ((const float4*)W_in)[idx];
    ushort4 o = { f2bf(v.x), f2bf(v.y), f2bf(v.z), f2bf(v.w) };
    ((ushort4*)WinB)[idx] = o;
  }
  if (idx < 524288){
    float4 v = ((const float4*)W_out)[idx];
    ushort4 o = { f2bf(v.x), f2bf(v.y), f2bf(v.z), f2bf(v.w) };
    ((ushort4*)WoutB)[idx] = o;
  }
  if (idx < NL_*64*DI_/4){   // wxB: straight bf16 copy of W_x (NT layout already)
    float4 v = ((const float4*)W_x)[idx];
    ushort4 o = { f2bf(v.x), f2bf(v.y), f2bf(v.z), f2bf(v.w) };
    ((ushort4*)wxB)[idx] = o;
  }
  if (idx < NL_*DTR_*DI_){
    int l = idx / (DTR_*DI_); int rem = idx % (DTR_*DI_);
    int r = rem / DI_; int d = rem % DI_;
    wdtT[idx] = W_dt[((size_t)l*DI_ + d)*DTR_ + r];
  }
  if (idx < 512*128){
    int d = idx >> 7, kk = idx & 127;
    peWb[idx] = (kk < 112) ? f2bf(peW[d*112 + kk]) : (u16)0;
  }
}

extern "C" void kernel_launch(void* const* d_in, const int* in_sizes, int n_in,
                              void* d_out, int out_size, void* d_ws, size_t ws_size,
                              hipStream_t stream) {
  const float* x      = (const float*)d_in[0];
  const float* in_g   = (const float*)d_in[1];
  const float* in_b   = (const float*)d_in[2];
  const float* pe_W   = (const float*)d_in[3];
  const float* pe_b   = (const float*)d_in[4];
  const float* ln_g   = (const float*)d_in[5];
  const float* ln_b   = (const float*)d_in[6];
  const float* W_in   = (const float*)d_in[7];
  const float* conv_W = (const float*)d_in[8];
  const float* conv_b = (const float*)d_in[9];
  const float* W_x    = (const float*)d_in[10];
  const float* W_dt   = (const float*)d_in[11];
  const float* b_dt   = (const float*)d_in[12];
  const float* A_log  = (const float*)d_in[13];
  const float* Dskip  = (const float*)d_in[14];
  const float* W_out  = (const float*)d_in[15];
  const float* fn_g   = (const float*)d_in[16];
  const float* fn_b   = (const float*)d_in[17];
  const float* hW1    = (const float*)d_in[18];
  const float* hb1    = (const float*)d_in[19];
  const float* hW2    = (const float*)d_in[20];
  const float* hb2    = (const float*)d_in[21];

  float* ws    = (float*)d_ws;
  float* h     = ws;                    // 1,048,576 f
  float* un    = h     + 1048576;       // 1,048,576 f
  float* xz    = un    + 1048576;       // 4,194,304 f
  float* xc    = xz    + 4194304;       // 2,097,152 f
  float* dblb  = xc    + 2097152;       //   131,072 f
  float* delta = dblb  + 131072;        // 2,097,152 f
  float* y     = delta + 2097152;       // 2,097,152 f  (overlays: xpb prologue, xcb conv, hend scan)
  float* wdtT  = y     + 2097152;       //   131,072 f
  u16*   wxB   = (u16*)(wdtT + 131072);         //   262,144 u16 (=131,072 f)
  float* bf_rgn= wdtT + 131072 + 131072;
  u16*   unb   = (u16*)bf_rgn;                  // 1,048,576 u16
  u16*   yb    = (u16*)(bf_rgn + 524288);       // 2,097,152 u16
  u16*   WinB  = (u16*)(bf_rgn + 524288 + 1048576);            // 4,194,304 u16
  u16*   WoutB = (u16*)(bf_rgn + 524288 + 1048576 + 2097152);  // 2,097,152 u16
  u16*   peWb  = (u16*)(bf_rgn + 524288 + 1048576 + 2097152 + 1048576); // 65,536 u16
  float* aprod = bf_rgn + 524288 + 1048576 + 2097152 + 1048576 + 32768; // 2,097,152 f
  // end ≈ 79.3 MB
  float* hend  = y;                     // [B*NCH][DI][NS]; becomes hin after pass B
  u16*   xcb   = (u16*)y;               // bf16 xc [2048][1024]; free before scan_part
  u16*   xpb   = (u16*)y;               // prologue-only: bf16 patches [2048][128]
  float* dblpart = aprod;               // [4][2048][64] = 524,288 f; free before scan_part
  float* partial = xz;                  // epilogue-only (64*128*8 = 65,536 f)
  float* t1      = xz + 262144;

  prep_kernel<<<4096, 256, 0, stream>>>(W_dt, W_x, W_in, W_out, pe_W,
                                        wdtT, wxB, WinB, WoutB, peWb);
  ln7_kernel<<<(B_*SEQ_+255)/256, 256, 0, stream>>>(x, in_g, in_b, xpb);
  // patch-embed as bf16 GEMM: h[2048][512] = xpb[2048][128] @ peWb[512][128]^T + pe_b
  gemm_bf16<64,128,false,true><<<dim3(DM_/128, TOK_/64), 256, 0, stream>>>(
      xpb, peWb, h, pe_b, 128, 128, 128, DM_);

  for (int l = 0; l < NL_; l++){
    ln512_kernel<<<TOK_/4, 256, 0, stream>>>(h, ln_g + l*DM_, ln_b + l*DM_, un, unb);
    gemm_bf16<64,128,false,false><<<dim3(2*DI_/128, TOK_/64), 256, 0, stream>>>(
        unb, WinB + (size_t)l*2*DI_*DM_, xz, nullptr, DM_, DM_, DM_, 2*DI_);
    conv_silu_kernel<<<(TOK_*DI_/4)/256, 256, 0, stream>>>(
        xz, conv_W + (size_t)l*DI_*DC_, conv_b + (size_t)l*DI_, xc, xcb);
    // dbl partials: [4][2048][64] = xcb @ W_x^T split-K
    dblpart_kernel<<<dim3(TOK_/64, 4), 256, 0, stream>>>(
        xcb, wxB + (size_t)l*64*DI_, dblpart);
    delta_kernel<<<TOK_/16, 256, 0, stream>>>(
        dblpart, wdtT + (size_t)l*DTR_*DI_, b_dt + (size_t)l*DI_, dblb, delta);
    scan_part_kernel<<<dim3(DI_/256, B_*NCH_), 256, 0, stream>>>(
        delta, xc, dblb, A_log + (size_t)l*DI_*NS_, hend, aprod);
    scan_fix_kernel<<<(B_*DI_*NS_)/256, 256, 0, stream>>>(aprod, hend);
    scan_final_kernel<<<dim3(DI_/256, B_*NCH_), 256, 0, stream>>>(
        delta, xc, dblb, xz, Dskip + (size_t)l*DI_, A_log + (size_t)l*DI_*NS_, hend, yb);
    gemm_bf16<64,64,true,false><<<dim3(DM_/64, TOK_/64), 256, 0, stream>>>(
        yb, WoutB + (size_t)l*DM_*DI_, h, nullptr, DI_, DI_, DI_, DM_);
  }

  ln512_kernel<<<TOK_/4, 256, 0, stream>>>(h, fn_g, fn_b, un, unb);
  head1_kernel<<<dim3(32, 64), 256, 0, stream>>>(un, hW1, partial);
  head_combine_kernel<<<4, 256, 0, stream>>>(partial, hb1, t1);
  head2_kernel<<<6, 128, 0, stream>>>(t1, hW2, hb2, (float*)d_out);
}

// Round 9
// 576.481 us; speedup vs baseline: 1.1389x; 1.1389x over previous
//
#include <hip/hip_runtime.h>
#include <hip/hip_bf16.h>
#include <math.h>

#define B_    8
#define SEQ_  4096
#define CIN_  7
#define DM_   512
#define NL_   4
#define PL_   16
#define NP_   256
#define NS_   16
#define DC_   4
#define DI_   1024
#define DTR_  32
#define CD_   64
#define PRED_ 96
#define TOK_  (B_*NP_)   // 2048
#define EPS_  1e-5f
#define CL_   16         // scan chunk length
#define NCH_  (NP_/CL_)  // 16 chunks

typedef unsigned short u16;
typedef __attribute__((ext_vector_type(8))) short short8;
typedef __attribute__((ext_vector_type(4))) float floatx4;

__device__ __forceinline__ float silu_f(float x){ return x / (1.f + __expf(-x)); }
__device__ __forceinline__ float softplus_f(float x){ return x > 20.f ? x : log1pf(__expf(x)); }
__device__ __forceinline__ u16 f2bf(float f){
  union { __hip_bfloat16 h; u16 u; } cv; cv.h = __float2bfloat16(f); return cv.u;
}
#define GLDS16(g, l) __builtin_amdgcn_global_load_lds( \
    (const __attribute__((address_space(1))) void*)(g), \
    (__attribute__((address_space(3))) void*)(l), 16, 0, 0)

// ---------------- LN over CIN=7 -> bf16 patch rows [2048][128] (zero-padded 112..127) ----------------
__global__ void ln7_kernel(const float* __restrict__ x, const float* __restrict__ g,
                           const float* __restrict__ b, u16* __restrict__ xpb){
  int i = blockIdx.x*256 + threadIdx.x; // over B*SEQ
  if (i >= B_*SEQ_) return;
  float v[CIN_]; float m = 0.f;
  #pragma unroll
  for (int c=0;c<CIN_;c++){ v[c]=x[i*CIN_+c]; m+=v[c]; }
  m *= (1.f/CIN_);
  float var = 0.f;
  #pragma unroll
  for (int c=0;c<CIN_;c++){ float d=v[c]-m; var+=d*d; }
  var *= (1.f/CIN_);
  float r = rsqrtf(var + EPS_);
  int bn = i >> 4, p = i & 15;            // token, pos-in-patch
  u16* row = xpb + (size_t)bn*128;
  #pragma unroll
  for (int c=0;c<CIN_;c++) row[c*16+p] = f2bf((v[c]-m)*r*g[c]+b[c]);
  row[112+p] = 0;
}

// ---------------- LN over DM=512, wave-per-token, fp32+bf16 out ----------------
__global__ __launch_bounds__(256) void ln512_kernel(const float* __restrict__ in,
    const float* __restrict__ g, const float* __restrict__ b,
    float* __restrict__ out, u16* __restrict__ outb){
  int tid = threadIdx.x;
  int wv = tid>>6, lane = tid&63;
  int t = blockIdx.x*4 + wv;
  const float4* row = (const float4*)(in + (size_t)t*DM_);
  float4 v0 = row[lane], v1 = row[64+lane];
  float s = v0.x+v0.y+v0.z+v0.w + v1.x+v1.y+v1.z+v1.w;
  #pragma unroll
  for (int o=1;o<64;o<<=1) s += __shfl_xor(s,o);
  float m = s*(1.f/DM_);
  float d0x=v0.x-m,d0y=v0.y-m,d0z=v0.z-m,d0w=v0.w-m;
  float d1x=v1.x-m,d1y=v1.y-m,d1z=v1.z-m,d1w=v1.w-m;
  float q = d0x*d0x+d0y*d0y+d0z*d0z+d0w*d0w + d1x*d1x+d1y*d1y+d1z*d1z+d1w*d1w;
  #pragma unroll
  for (int o=1;o<64;o<<=1) q += __shfl_xor(q,o);
  float r = rsqrtf(q*(1.f/DM_) + EPS_);
  float4 g0 = ((const float4*)g)[lane], g1 = ((const float4*)g)[64+lane];
  float4 b0 = ((const float4*)b)[lane], b1 = ((const float4*)b)[64+lane];
  float4 o0 = { d0x*r*g0.x+b0.x, d0y*r*g0.y+b0.y, d0z*r*g0.z+b0.z, d0w*r*g0.w+b0.w };
  float4 o1 = { d1x*r*g1.x+b1.x, d1y*r*g1.y+b1.y, d1z*r*g1.z+b1.z, d1w*r*g1.w+b1.w };
  ((float4*)(out + (size_t)t*DM_))[lane]    = o0;
  ((float4*)(out + (size_t)t*DM_))[64+lane] = o1;
  ushort4 p0 = { f2bf(o0.x), f2bf(o0.y), f2bf(o0.z), f2bf(o0.w) };
  ushort4 p1 = { f2bf(o1.x), f2bf(o1.y), f2bf(o1.z), f2bf(o1.w) };
  ((ushort4*)(outb + (size_t)t*DM_))[lane]    = p0;
  ((ushort4*)(outb + (size_t)t*DM_))[64+lane] = p1;
}

// ---------------- bf16 MFMA NT GEMM: C[M,N](f32) = A[M,K]*B[N,K]^T (+bias) ----------------
template<int BM, int BN, bool ACC, bool BIAS>
__global__ __launch_bounds__(256) void gemm_bf16(const u16* __restrict__ A,
    const u16* __restrict__ Bw, float* __restrict__ C, const float* __restrict__ bias,
    int K, int lda, int ldb, int ldc){
  constexpr int MI = BM/32, NI = BN/32;
  __shared__ __align__(16) u16 As[BM*64];
  __shared__ __align__(16) u16 Bs[BN*64];
  int tid = threadIdx.x;
  int wave = __builtin_amdgcn_readfirstlane(tid>>6);
  int lane = tid&63;
  int wm = wave>>1, wn = wave&1;
  int quad = lane>>4, l16 = lane&15;
  int bm = blockIdx.y*BM, bn = blockIdx.x*BN;
  int r8 = lane>>3, sseg = lane&7;
  int gseg = sseg ^ r8;                  // global k-seg this lane fetches
  floatx4 acc[MI][NI] = {};
  for (int k0 = 0; k0 < K; k0 += 64){
    #pragma unroll
    for (int r = 0; r < BM/32; r++){
      int rowb = (r*4 + wave)*8;
      const u16* gp = A + (size_t)(bm + rowb + r8)*lda + k0 + gseg*8;
      GLDS16(gp, &As[rowb*64]);
    }
    #pragma unroll
    for (int r = 0; r < BN/32; r++){
      int rowb = (r*4 + wave)*8;
      const u16* gp = Bw + (size_t)(bn + rowb + r8)*ldb + k0 + gseg*8;
      GLDS16(gp, &Bs[rowb*64]);
    }
    __syncthreads();
    #pragma unroll
    for (int kh = 0; kh < 2; kh++){
      short8 af[MI], bfr[NI];
      #pragma unroll
      for (int i = 0; i < MI; i++){
        int row = wm*(BM/2)+i*16+l16;
        af[i] = *(short8*)&As[row*64 + (((kh*4+quad)^(row&7))*8)];
      }
      #pragma unroll
      for (int j = 0; j < NI; j++){
        int row = wn*(BN/2)+j*16+l16;
        bfr[j] = *(short8*)&Bs[row*64 + (((kh*4+quad)^(row&7))*8)];
      }
      #pragma unroll
      for (int i = 0; i < MI; i++)
        #pragma unroll
        for (int j = 0; j < NI; j++)
          acc[i][j] = __builtin_amdgcn_mfma_f32_16x16x32_bf16(af[i], bfr[j], acc[i][j], 0, 0, 0);
    }
    __syncthreads();
  }
  #pragma unroll
  for (int i = 0; i < MI; i++){
    #pragma unroll
    for (int j = 0; j < NI; j++){
      #pragma unroll
      for (int r = 0; r < 4; r++){
        int m  = bm + wm*(BM/2) + i*16 + quad*4 + r;
        int nn = bn + wn*(BN/2) + j*16 + l16;
        float v = acc[i][j][r];
        if (ACC) C[(size_t)m*ldc+nn] += v;
        else     C[(size_t)m*ldc+nn]  = BIAS ? v + bias[nn] : v;
      }
    }
  }
}

// ---------------- dbl split-K partial GEMM: part[kc][64t][64e] over K=256 chunk ----------------
__global__ __launch_bounds__(256) void dblpart_kernel(const u16* __restrict__ A,
    const u16* __restrict__ Bw, float* __restrict__ part){
  __shared__ __align__(16) u16 As[64*64];
  __shared__ __align__(16) u16 Bs[64*64];
  int tid = threadIdx.x;
  int wave = __builtin_amdgcn_readfirstlane(tid>>6);
  int lane = tid&63;
  int wm = wave>>1, wn = wave&1;
  int quad = lane>>4, l16 = lane&15;
  int bm = blockIdx.x*64;
  int kc = blockIdx.y;                 // 0..3, K chunk of 256
  int r8 = lane>>3, sseg = lane&7;
  int gseg = sseg ^ r8;
  floatx4 acc[2][2] = {};
  for (int k0 = kc*256; k0 < kc*256 + 256; k0 += 64){
    #pragma unroll
    for (int r = 0; r < 2; r++){
      int rowb = (r*4 + wave)*8;
      GLDS16(A  + (size_t)(bm + rowb + r8)*DI_ + k0 + gseg*8, &As[rowb*64]);
      GLDS16(Bw + (size_t)(     rowb + r8)*DI_ + k0 + gseg*8, &Bs[rowb*64]);
    }
    __syncthreads();
    #pragma unroll
    for (int kh = 0; kh < 2; kh++){
      short8 af[2], bfr[2];
      #pragma unroll
      for (int i = 0; i < 2; i++){
        int row = wm*32+i*16+l16;
        af[i] = *(short8*)&As[row*64 + (((kh*4+quad)^(row&7))*8)];
      }
      #pragma unroll
      for (int j = 0; j < 2; j++){
        int row = wn*32+j*16+l16;
        bfr[j] = *(short8*)&Bs[row*64 + (((kh*4+quad)^(row&7))*8)];
      }
      #pragma unroll
      for (int i = 0; i < 2; i++)
        #pragma unroll
        for (int j = 0; j < 2; j++)
          acc[i][j] = __builtin_amdgcn_mfma_f32_16x16x32_bf16(af[i], bfr[j], acc[i][j], 0, 0, 0);
    }
    __syncthreads();
  }
  float* dst = part + (size_t)kc*TOK_*64;
  #pragma unroll
  for (int i = 0; i < 2; i++)
    #pragma unroll
    for (int j = 0; j < 2; j++)
      #pragma unroll
      for (int r = 0; r < 4; r++){
        int m  = bm + wm*32 + i*16 + quad*4 + r;
        int nn = wn*32 + j*16 + l16;
        dst[(size_t)m*64+nn] = acc[i][j][r];
      }
}

// ---------------- dbl partial sum: dbl = sum_kc part[kc] ----------------
__global__ __launch_bounds__(256) void dblsum_kernel(const float* __restrict__ part,
    float* __restrict__ dbl){
  int idx = blockIdx.x*256 + threadIdx.x;  // over TOK*64/4 float4s
  float4 a = ((const float4*)part)[idx];
  float4 b = ((const float4*)(part + (size_t)TOK_*64))[idx];
  float4 c = ((const float4*)(part + (size_t)2*TOK_*64))[idx];
  float4 d = ((const float4*)(part + (size_t)3*TOK_*64))[idx];
  float4 o = { a.x+b.x+c.x+d.x, a.y+b.y+c.y+d.y, a.z+b.z+c.z+d.z, a.w+b.w+c.w+d.w };
  ((float4*)dbl)[idx] = o;
}

// ---------------- causal depthwise conv (DC=4) + bias + silu -> xc fp32 + xcb bf16 ----------------
__global__ void conv_silu_kernel(const float* __restrict__ xz, const float* __restrict__ cW,
                                 const float* __restrict__ cb, float* __restrict__ xc,
                                 u16* __restrict__ xcb){
  int idx = blockIdx.x*256 + threadIdx.x;   // over TOK*DI/4
  if (idx >= TOK_*DI_/4) return;
  int c4 = idx & (DI_/4 - 1); int t = idx >> 8;
  int l = t & (NP_-1);
  int c = c4*4;
  float4 acc = *(const float4*)&cb[c];
  float wa[4], wb[4], wc[4], wd[4];
  *(float4*)wa = *(const float4*)&cW[(c+0)*DC_];
  *(float4*)wb = *(const float4*)&cW[(c+1)*DC_];
  *(float4*)wc = *(const float4*)&cW[(c+2)*DC_];
  *(float4*)wd = *(const float4*)&cW[(c+3)*DC_];
  const float* base = xz + (size_t)t*(2*DI_) + c;
  #pragma unroll
  for (int k = 0; k < DC_; k++){
    if (l - 3 + k >= 0){
      float4 xv = *(const float4*)(base + (k-3)*(2*DI_));
      acc.x += xv.x*wa[k];
      acc.y += xv.y*wb[k];
      acc.z += xv.z*wc[k];
      acc.w += xv.w*wd[k];
    }
  }
  acc.x = silu_f(acc.x); acc.y = silu_f(acc.y);
  acc.z = silu_f(acc.z); acc.w = silu_f(acc.w);
  *(float4*)&xc[(size_t)t*DI_ + c] = acc;
  ushort4 pb = { f2bf(acc.x), f2bf(acc.y), f2bf(acc.z), f2bf(acc.w) };
  *(ushort4*)&xcb[(size_t)t*DI_ + c] = pb;
}

// ---------------- delta = softplus(dt @ W_dt^T + b_dt), 16 t per block ----------------
__global__ __launch_bounds__(256) void delta_kernel(const float* __restrict__ dbl,
    const float* __restrict__ wdtT, const float* __restrict__ bdt, float* __restrict__ delta){
  __shared__ float sdt[16][DTR_];
  int tid = threadIdx.x;
  int t0 = blockIdx.y*16;
  int d = blockIdx.x*256 + tid;
  for (int i = tid; i < 16*DTR_; i += 256){
    int t = i >> 5, r = i & 31;
    sdt[t][r] = dbl[(size_t)(t0 + t)*64 + r];
  }
  float wv[DTR_];
  #pragma unroll
  for (int r = 0; r < DTR_; r++) wv[r] = wdtT[(size_t)r*DI_ + d];
  float bb = bdt[d];
  __syncthreads();
  #pragma unroll 4
  for (int t = 0; t < 16; t++){
    float acc = bb;
    #pragma unroll
    for (int r = 0; r < DTR_; r++) acc += sdt[t][r]*wv[r];
    delta[(size_t)(t0 + t)*DI_ + d] = softplus_f(acc);
  }
}

// ---------------- chunked selective scan, d-per-lane ----------------
__global__ __launch_bounds__(256) void scan_part_kernel(const float* __restrict__ delta,
    const float* __restrict__ xc, const float* __restrict__ dbl,
    const float* __restrict__ Alog, float* __restrict__ hend, float* __restrict__ aprod){
  __shared__ float sBC[CL_][32];
  int tid = threadIdx.x;
  int d = blockIdx.x*256 + tid;
  int bych = blockIdx.y;               // b*NCH + ch
  int b = bych >> 4, ch = bych & (NCH_-1);
  int base = b*NP_ + ch*CL_;
  for (int i = tid; i < CL_*32; i += 256){
    int t = i >> 5, c = i & 31;
    sBC[t][c] = dbl[(size_t)(base+t)*64 + 32 + c];
  }
  float A[NS_], h[NS_], pr[NS_];
  #pragma unroll
  for (int k = 0; k < NS_; k++){
    A[k] = -__expf(Alog[(size_t)d*NS_ + k]);
    h[k] = 0.f; pr[k] = 1.f;
  }
  __syncthreads();
  #pragma unroll
  for (int t = 0; t < CL_; t++){
    int row = base + t;
    float de = delta[(size_t)row*DI_ + d];
    float xv = xc[(size_t)row*DI_ + d];
    float cde = de*xv;
    #pragma unroll
    for (int k = 0; k < NS_; k++){
      float a = __expf(de*A[k]);
      h[k] = a*h[k] + cde*sBC[t][k];
      pr[k] *= a;
    }
  }
  size_t o = ((size_t)bych*DI_ + d)*NS_;
  #pragma unroll
  for (int k = 0; k < NS_; k++){ hend[o+k] = h[k]; aprod[o+k] = pr[k]; }
}

__global__ __launch_bounds__(256) void scan_fix_kernel(const float* __restrict__ aprod,
    float* __restrict__ hend){
  int id = blockIdx.x*256 + threadIdx.x;  // over B*DI*NS = 131072
  int nd = id & (DI_*NS_ - 1);
  int b  = id >> 14;
  float h = 0.f;
  #pragma unroll
  for (int ch = 0; ch < NCH_; ch++){
    size_t idx = (size_t)(b*NCH_ + ch)*(DI_*NS_) + nd;
    float ap = aprod[idx];
    float he = hend[idx];
    hend[idx] = h;
    h = ap*h + he;
  }
}

__global__ __launch_bounds__(256) void scan_final_kernel(const float* __restrict__ delta,
    const float* __restrict__ xc, const float* __restrict__ dbl,
    const float* __restrict__ xz, const float* __restrict__ Dv,
    const float* __restrict__ Alog, const float* __restrict__ hin,
    u16* __restrict__ yb){
  __shared__ float sBC[CL_][32];
  int tid = threadIdx.x;
  int d = blockIdx.x*256 + tid;
  int bych = blockIdx.y;
  int b = bych >> 4, ch = bych & (NCH_-1);
  int base = b*NP_ + ch*CL_;
  for (int i = tid; i < CL_*32; i += 256){
    int t = i >> 5, c = i & 31;
    sBC[t][c] = dbl[(size_t)(base+t)*64 + 32 + c];
  }
  float A[NS_], h[NS_];
  size_t o = ((size_t)bych*DI_ + d)*NS_;
  #pragma unroll
  for (int k = 0; k < NS_; k++){
    A[k] = -__expf(Alog[(size_t)d*NS_ + k]);
    h[k] = hin[o + k];
  }
  float Dvd = Dv[d];
  __syncthreads();
  #pragma unroll
  for (int t = 0; t < CL_; t++){
    int row = base + t;
    float de = delta[(size_t)row*DI_ + d];
    float xv = xc[(size_t)row*DI_ + d];
    float zz = xz[(size_t)row*(2*DI_) + DI_ + d];
    float cde = de*xv;
    float p = 0.f;
    #pragma unroll
    for (int k = 0; k < NS_; k++){
      float a = __expf(de*A[k]);
      h[k] = a*h[k] + cde*sBC[t][k];
      p += h[k]*sBC[t][16+k];
    }
    yb[(size_t)row*DI_ + d] = f2bf((p + xv*Dvd) * silu_f(zz));
  }
}

// ---------------- head GEMM1: wave-per-n, grid (32 nb, 128 kc), KLEN=1024 ----------------
__global__ __launch_bounds__(256) void head1_kernel(const float* __restrict__ u,
    const float* __restrict__ hW1, float* __restrict__ partial){
  const int KTOT = DM_*NP_;        // 131072
  int nb = blockIdx.x;             // 0..31 (4 n per block, wave-per-n)
  int kc = blockIdx.y;             // 0..127
  int tid = threadIdx.x;
  int lane = tid & 63, wv = tid >> 6;
  int n = nb*4 + wv;
  const float* wrow = hW1 + (size_t)n*KTOT;
  float acc[8] = {};
  int kb = kc*1024 + lane*4;
  #pragma unroll
  for (int it = 0; it < 4; it++){
    int k = kb + it*256;
    float4 w4 = *(const float4*)&wrow[k];
    #pragma unroll
    for (int m = 0; m < 8; m++){
      float4 u4 = *(const float4*)&u[(size_t)m*KTOT + k];
      acc[m] += u4.x*w4.x + u4.y*w4.y + u4.z*w4.z + u4.w*w4.w;
    }
  }
  #pragma unroll
  for (int m = 0; m < 8; m++){
    float v = acc[m];
    v += __shfl_xor(v,1); v += __shfl_xor(v,2); v += __shfl_xor(v,4);
    v += __shfl_xor(v,8); v += __shfl_xor(v,16); v += __shfl_xor(v,32);
    acc[m] = v;
  }
  if (lane == 0){
    float* dst = partial + ((size_t)kc*128 + n)*8;
    #pragma unroll
    for (int m = 0; m < 8; m++) dst[m] = acc[m];
  }
}

__global__ void head_combine_kernel(const float* __restrict__ partial,
    const float* __restrict__ hb1, float* __restrict__ t1){
  int idx = blockIdx.x*256 + threadIdx.x;  // n*8+m, 1024 total
  if (idx >= 128*8) return;
  int n = idx >> 3, m = idx & 7;
  float s = hb1[n];
  for (int kc = 0; kc < 128; kc++) s += partial[((size_t)kc*128 + n)*8 + m];
  float ge = 0.5f*s*(1.f + erff(s*0.70710678118f));
  t1[m*128 + n] = ge;
}

__global__ void head2_kernel(const float* __restrict__ t1, const float* __restrict__ hW2,
                             const float* __restrict__ hb2, float* __restrict__ out){
  int idx = blockIdx.x*128 + threadIdx.x;  // 8*96
  if (idx >= B_*PRED_) return;
  int m = idx / PRED_, q = idx % PRED_;
  float s = hb2[q];
  #pragma unroll 16
  for (int k = 0; k < 2*CD_; k++) s += t1[m*128 + k]*hW2[q*128 + k];
  out[idx] = s;
}

// ---------------- prep: vectorized bf16 conversions + transposes ----------------
__global__ __launch_bounds__(256) void prep_kernel(const float* __restrict__ W_dt,
    const float* __restrict__ W_x, const float* __restrict__ W_in,
    const float* __restrict__ W_out, const float* __restrict__ peW,
    float* __restrict__ wdtT, u16* __restrict__ wxB,
    u16* __restrict__ WinB, u16* __restrict__ WoutB, u16* __restrict__ peWb){
  int idx = blockIdx.x*256 + threadIdx.x;   // 1,048,576 threads
  {
    float4 v = ((const float4*)W_in)[idx];
    ushort4 o = { f2bf(v.x), f2bf(v.y), f2bf(v.z), f2bf(v.w) };
    ((ushort4*)WinB)[idx] = o;
  }
  if (idx < 524288){
    float4 v = ((const float4*)W_out)[idx];
    ushort4 o = { f2bf(v.x), f2bf(v.y), f2bf(v.z), f2bf(v.w) };
    ((ushort4*)WoutB)[idx] = o;
  }
  if (idx < NL_*64*DI_/4){   // wxB: straight bf16 copy of W_x (NT layout already)
    float4 v = ((const float4*)W_x)[idx];
    ushort4 o = { f2bf(v.x), f2bf(v.y), f2bf(v.z), f2bf(v.w) };
    ((ushort4*)wxB)[idx] = o;
  }
  if (idx < NL_*DTR_*DI_){
    int l = idx / (DTR_*DI_); int rem = idx % (DTR_*DI_);
    int r = rem / DI_; int d = rem % DI_;
    wdtT[idx] = W_dt[((size_t)l*DI_ + d)*DTR_ + r];
  }
  if (idx < 512*128){
    int d = idx >> 7, kk = idx & 127;
    peWb[idx] = (kk < 112) ? f2bf(peW[d*112 + kk]) : (u16)0;
  }
}

extern "C" void kernel_launch(void* const* d_in, const int* in_sizes, int n_in,
                              void* d_out, int out_size, void* d_ws, size_t ws_size,
                              hipStream_t stream) {
  const float* x      = (const float*)d_in[0];
  const float* in_g   = (const float*)d_in[1];
  const float* in_b   = (const float*)d_in[2];
  const float* pe_W   = (const float*)d_in[3];
  const float* pe_b   = (const float*)d_in[4];
  const float* ln_g   = (const float*)d_in[5];
  const float* ln_b   = (const float*)d_in[6];
  const float* W_in   = (const float*)d_in[7];
  const float* conv_W = (const float*)d_in[8];
  const float* conv_b = (const float*)d_in[9];
  const float* W_x    = (const float*)d_in[10];
  const float* W_dt   = (const float*)d_in[11];
  const float* b_dt   = (const float*)d_in[12];
  const float* A_log  = (const float*)d_in[13];
  const float* Dskip  = (const float*)d_in[14];
  const float* W_out  = (const float*)d_in[15];
  const float* fn_g   = (const float*)d_in[16];
  const float* fn_b   = (const float*)d_in[17];
  const float* hW1    = (const float*)d_in[18];
  const float* hb1    = (const float*)d_in[19];
  const float* hW2    = (const float*)d_in[20];
  const float* hb2    = (const float*)d_in[21];

  float* ws    = (float*)d_ws;
  float* h     = ws;                    // 1,048,576 f
  float* un    = h     + 1048576;       // 1,048,576 f
  float* xz    = un    + 1048576;       // 4,194,304 f
  float* xc    = xz    + 4194304;       // 2,097,152 f
  float* dblb  = xc    + 2097152;       //   131,072 f
  float* delta = dblb  + 131072;        // 2,097,152 f
  float* y     = delta + 2097152;       // 2,097,152 f  (overlays: xpb prologue, xcb conv, hend scan)
  float* wdtT  = y     + 2097152;       //   131,072 f
  u16*   wxB   = (u16*)(wdtT + 131072);         //   262,144 u16 (=131,072 f)
  float* bf_rgn= wdtT + 131072 + 131072;
  u16*   unb   = (u16*)bf_rgn;                  // 1,048,576 u16
  u16*   yb    = (u16*)(bf_rgn + 524288);       // 2,097,152 u16
  u16*   WinB  = (u16*)(bf_rgn + 524288 + 1048576);            // 4,194,304 u16
  u16*   WoutB = (u16*)(bf_rgn + 524288 + 1048576 + 2097152);  // 2,097,152 u16
  u16*   peWb  = (u16*)(bf_rgn + 524288 + 1048576 + 2097152 + 1048576); // 65,536 u16
  float* aprod = bf_rgn + 524288 + 1048576 + 2097152 + 1048576 + 32768; // 2,097,152 f
  // end ≈ 79.3 MB
  float* hend  = y;                     // [B*NCH][DI][NS]; becomes hin after pass B
  u16*   xcb   = (u16*)y;               // bf16 xc [2048][1024]; free before scan_part
  u16*   xpb   = (u16*)y;               // prologue-only: bf16 patches [2048][128]
  float* dblpart = aprod;               // [4][2048][64] = 524,288 f; consumed before scan_part
  float* partial = xz;                  // epilogue-only (128*128*8 = 131,072 f)
  float* t1      = xz + 262144;

  prep_kernel<<<4096, 256, 0, stream>>>(W_dt, W_x, W_in, W_out, pe_W,
                                        wdtT, wxB, WinB, WoutB, peWb);
  ln7_kernel<<<(B_*SEQ_+255)/256, 256, 0, stream>>>(x, in_g, in_b, xpb);
  // patch-embed as bf16 GEMM: h[2048][512] = xpb[2048][128] @ peWb[512][128]^T + pe_b
  gemm_bf16<64,128,false,true><<<dim3(DM_/128, TOK_/64), 256, 0, stream>>>(
      xpb, peWb, h, pe_b, 128, 128, 128, DM_);

  for (int l = 0; l < NL_; l++){
    ln512_kernel<<<TOK_/4, 256, 0, stream>>>(h, ln_g + l*DM_, ln_b + l*DM_, un, unb);
    gemm_bf16<64,128,false,false><<<dim3(2*DI_/128, TOK_/64), 256, 0, stream>>>(
        unb, WinB + (size_t)l*2*DI_*DM_, xz, nullptr, DM_, DM_, DM_, 2*DI_);
    conv_silu_kernel<<<(TOK_*DI_/4)/256, 256, 0, stream>>>(
        xz, conv_W + (size_t)l*DI_*DC_, conv_b + (size_t)l*DI_, xc, xcb);
    // dbl partials: [4][2048][64] = xcb @ W_x^T split-K
    dblpart_kernel<<<dim3(TOK_/64, 4), 256, 0, stream>>>(
        xcb, wxB + (size_t)l*64*DI_, dblpart);
    dblsum_kernel<<<(TOK_*64/4)/256, 256, 0, stream>>>(dblpart, dblb);
    delta_kernel<<<dim3(DI_/256, TOK_/16), 256, 0, stream>>>(
        dblb, wdtT + (size_t)l*DTR_*DI_, b_dt + (size_t)l*DI_, delta);
    scan_part_kernel<<<dim3(DI_/256, B_*NCH_), 256, 0, stream>>>(
        delta, xc, dblb, A_log + (size_t)l*DI_*NS_, hend, aprod);
    scan_fix_kernel<<<(B_*DI_*NS_)/256, 256, 0, stream>>>(aprod, hend);
    scan_final_kernel<<<dim3(DI_/256, B_*NCH_), 256, 0, stream>>>(
        delta, xc, dblb, xz, Dskip + (size_t)l*DI_, A_log + (size_t)l*DI_*NS_, hend, yb);
    gemm_bf16<64,64,true,false><<<dim3(DM_/64, TOK_/64), 256, 0, stream>>>(
        yb, WoutB + (size_t)l*DM_*DI_, h, nullptr, DI_, DI_, DI_, DM_);
  }

  ln512_kernel<<<TOK_/4, 256, 0, stream>>>(h, fn_g, fn_b, un, unb);
  head1_kernel<<<dim3(32, 128), 256, 0, stream>>>(un, hW1, partial);
  head_combine_kernel<<<4, 256, 0, stream>>>(partial, hb1, t1);
  head2_kernel<<<6, 128, 0, stream>>>(t1, hW2, hb2, (float*)d_out);
}

// Round 10
// 553.052 us; speedup vs baseline: 1.1871x; 1.0424x over previous
//
#include <hip/hip_runtime.h>
#include <hip/hip_bf16.h>
#include <math.h>

#define B_    8
#define SEQ_  4096
#define CIN_  7
#define DM_   512
#define NL_   4
#define PL_   16
#define NP_   256
#define NS_   16
#define DC_   4
#define DI_   1024
#define DTR_  32
#define CD_   64
#define PRED_ 96
#define TOK_  (B_*NP_)   // 2048
#define KTOT_ (DM_*NP_)  // 131072
#define EPS_  1e-5f
#define CL_   16         // scan chunk length
#define NCH_  (NP_/CL_)  // 16 chunks

typedef unsigned short u16;
typedef __attribute__((ext_vector_type(8))) short short8;
typedef __attribute__((ext_vector_type(4))) float floatx4;

__device__ __forceinline__ float silu_f(float x){ return x / (1.f + __expf(-x)); }
__device__ __forceinline__ float softplus_f(float x){ return x > 20.f ? x : log1pf(__expf(x)); }
__device__ __forceinline__ u16 f2bf(float f){
  union { __hip_bfloat16 h; u16 u; } cv; cv.h = __float2bfloat16(f); return cv.u;
}
__device__ __forceinline__ float bf2f(u16 u){
  union { unsigned int i; float f; } cv; cv.i = ((unsigned int)u) << 16; return cv.f;
}
#define GLDS16(g, l) __builtin_amdgcn_global_load_lds( \
    (const __attribute__((address_space(1))) void*)(g), \
    (__attribute__((address_space(3))) void*)(l), 16, 0, 0)

// ---------------- LN over CIN=7 -> bf16 patch rows [2048][128] (zero-padded 112..127) ----------------
__global__ void ln7_kernel(const float* __restrict__ x, const float* __restrict__ g,
                           const float* __restrict__ b, u16* __restrict__ xpb){
  int i = blockIdx.x*256 + threadIdx.x; // over B*SEQ
  if (i >= B_*SEQ_) return;
  float v[CIN_]; float m = 0.f;
  #pragma unroll
  for (int c=0;c<CIN_;c++){ v[c]=x[i*CIN_+c]; m+=v[c]; }
  m *= (1.f/CIN_);
  float var = 0.f;
  #pragma unroll
  for (int c=0;c<CIN_;c++){ float d=v[c]-m; var+=d*d; }
  var *= (1.f/CIN_);
  float r = rsqrtf(var + EPS_);
  int bn = i >> 4, p = i & 15;            // token, pos-in-patch
  u16* row = xpb + (size_t)bn*128;
  #pragma unroll
  for (int c=0;c<CIN_;c++) row[c*16+p] = f2bf((v[c]-m)*r*g[c]+b[c]);
  row[112+p] = 0;
}

// ---------------- LN over DM=512, wave-per-token, bf16 out ----------------
__global__ __launch_bounds__(256) void ln512_kernel(const float* __restrict__ in,
    const float* __restrict__ g, const float* __restrict__ b, u16* __restrict__ outb){
  int tid = threadIdx.x;
  int wv = tid>>6, lane = tid&63;
  int t = blockIdx.x*4 + wv;
  const float4* row = (const float4*)(in + (size_t)t*DM_);
  float4 v0 = row[lane], v1 = row[64+lane];
  float s = v0.x+v0.y+v0.z+v0.w + v1.x+v1.y+v1.z+v1.w;
  #pragma unroll
  for (int o=1;o<64;o<<=1) s += __shfl_xor(s,o);
  float m = s*(1.f/DM_);
  float d0x=v0.x-m,d0y=v0.y-m,d0z=v0.z-m,d0w=v0.w-m;
  float d1x=v1.x-m,d1y=v1.y-m,d1z=v1.z-m,d1w=v1.w-m;
  float q = d0x*d0x+d0y*d0y+d0z*d0z+d0w*d0w + d1x*d1x+d1y*d1y+d1z*d1z+d1w*d1w;
  #pragma unroll
  for (int o=1;o<64;o<<=1) q += __shfl_xor(q,o);
  float r = rsqrtf(q*(1.f/DM_) + EPS_);
  float4 g0 = ((const float4*)g)[lane], g1 = ((const float4*)g)[64+lane];
  float4 b0 = ((const float4*)b)[lane], b1 = ((const float4*)b)[64+lane];
  float4 o0 = { d0x*r*g0.x+b0.x, d0y*r*g0.y+b0.y, d0z*r*g0.z+b0.z, d0w*r*g0.w+b0.w };
  float4 o1 = { d1x*r*g1.x+b1.x, d1y*r*g1.y+b1.y, d1z*r*g1.z+b1.z, d1w*r*g1.w+b1.w };
  ushort4 p0 = { f2bf(o0.x), f2bf(o0.y), f2bf(o0.z), f2bf(o0.w) };
  ushort4 p1 = { f2bf(o1.x), f2bf(o1.y), f2bf(o1.z), f2bf(o1.w) };
  ((ushort4*)(outb + (size_t)t*DM_))[lane]    = p0;
  ((ushort4*)(outb + (size_t)t*DM_))[64+lane] = p1;
}

// ---------------- bf16 MFMA NT GEMM: C[M,N](f32) = A[M,K]*B[N,K]^T (+bias) ----------------
template<int BM, int BN, bool ACC, bool BIAS>
__global__ __launch_bounds__(256) void gemm_bf16(const u16* __restrict__ A,
    const u16* __restrict__ Bw, float* __restrict__ C, const float* __restrict__ bias,
    int K, int lda, int ldb, int ldc){
  constexpr int MI = BM/32, NI = BN/32;
  __shared__ __align__(16) u16 As[BM*64];
  __shared__ __align__(16) u16 Bs[BN*64];
  int tid = threadIdx.x;
  int wave = __builtin_amdgcn_readfirstlane(tid>>6);
  int lane = tid&63;
  int wm = wave>>1, wn = wave&1;
  int quad = lane>>4, l16 = lane&15;
  int bm = blockIdx.y*BM, bn = blockIdx.x*BN;
  int r8 = lane>>3, sseg = lane&7;
  int gseg = sseg ^ r8;                  // global k-seg this lane fetches
  floatx4 acc[MI][NI] = {};
  for (int k0 = 0; k0 < K; k0 += 64){
    #pragma unroll
    for (int r = 0; r < BM/32; r++){
      int rowb = (r*4 + wave)*8;
      const u16* gp = A + (size_t)(bm + rowb + r8)*lda + k0 + gseg*8;
      GLDS16(gp, &As[rowb*64]);
    }
    #pragma unroll
    for (int r = 0; r < BN/32; r++){
      int rowb = (r*4 + wave)*8;
      const u16* gp = Bw + (size_t)(bn + rowb + r8)*ldb + k0 + gseg*8;
      GLDS16(gp, &Bs[rowb*64]);
    }
    __syncthreads();
    #pragma unroll
    for (int kh = 0; kh < 2; kh++){
      short8 af[MI], bfr[NI];
      #pragma unroll
      for (int i = 0; i < MI; i++){
        int row = wm*(BM/2)+i*16+l16;
        af[i] = *(short8*)&As[row*64 + (((kh*4+quad)^(row&7))*8)];
      }
      #pragma unroll
      for (int j = 0; j < NI; j++){
        int row = wn*(BN/2)+j*16+l16;
        bfr[j] = *(short8*)&Bs[row*64 + (((kh*4+quad)^(row&7))*8)];
      }
      #pragma unroll
      for (int i = 0; i < MI; i++)
        #pragma unroll
        for (int j = 0; j < NI; j++)
          acc[i][j] = __builtin_amdgcn_mfma_f32_16x16x32_bf16(af[i], bfr[j], acc[i][j], 0, 0, 0);
    }
    __syncthreads();
  }
  #pragma unroll
  for (int i = 0; i < MI; i++){
    #pragma unroll
    for (int j = 0; j < NI; j++){
      #pragma unroll
      for (int r = 0; r < 4; r++){
        int m  = bm + wm*(BM/2) + i*16 + quad*4 + r;
        int nn = bn + wn*(BN/2) + j*16 + l16;
        float v = acc[i][j][r];
        if (ACC) C[(size_t)m*ldc+nn] += v;
        else     C[(size_t)m*ldc+nn]  = BIAS ? v + bias[nn] : v;
      }
    }
  }
}

// ---------------- dbl split-K partial GEMM: part[kc][64t][64e] over K=256 chunk ----------------
__global__ __launch_bounds__(256) void dblpart_kernel(const u16* __restrict__ A,
    const u16* __restrict__ Bw, float* __restrict__ part){
  __shared__ __align__(16) u16 As[64*64];
  __shared__ __align__(16) u16 Bs[64*64];
  int tid = threadIdx.x;
  int wave = __builtin_amdgcn_readfirstlane(tid>>6);
  int lane = tid&63;
  int wm = wave>>1, wn = wave&1;
  int quad = lane>>4, l16 = lane&15;
  int bm = blockIdx.x*64;
  int kc = blockIdx.y;                 // 0..3, K chunk of 256
  int r8 = lane>>3, sseg = lane&7;
  int gseg = sseg ^ r8;
  floatx4 acc[2][2] = {};
  for (int k0 = kc*256; k0 < kc*256 + 256; k0 += 64){
    #pragma unroll
    for (int r = 0; r < 2; r++){
      int rowb = (r*4 + wave)*8;
      GLDS16(A  + (size_t)(bm + rowb + r8)*DI_ + k0 + gseg*8, &As[rowb*64]);
      GLDS16(Bw + (size_t)(     rowb + r8)*DI_ + k0 + gseg*8, &Bs[rowb*64]);
    }
    __syncthreads();
    #pragma unroll
    for (int kh = 0; kh < 2; kh++){
      short8 af[2], bfr[2];
      #pragma unroll
      for (int i = 0; i < 2; i++){
        int row = wm*32+i*16+l16;
        af[i] = *(short8*)&As[row*64 + (((kh*4+quad)^(row&7))*8)];
      }
      #pragma unroll
      for (int j = 0; j < 2; j++){
        int row = wn*32+j*16+l16;
        bfr[j] = *(short8*)&Bs[row*64 + (((kh*4+quad)^(row&7))*8)];
      }
      #pragma unroll
      for (int i = 0; i < 2; i++)
        #pragma unroll
        for (int j = 0; j < 2; j++)
          acc[i][j] = __builtin_amdgcn_mfma_f32_16x16x32_bf16(af[i], bfr[j], acc[i][j], 0, 0, 0);
    }
    __syncthreads();
  }
  float* dst = part + (size_t)kc*TOK_*64;
  #pragma unroll
  for (int i = 0; i < 2; i++)
    #pragma unroll
    for (int j = 0; j < 2; j++)
      #pragma unroll
      for (int r = 0; r < 4; r++){
        int m  = bm + wm*32 + i*16 + quad*4 + r;
        int nn = wn*32 + j*16 + l16;
        dst[(size_t)m*64+nn] = acc[i][j][r];
      }
}

// ---------------- causal depthwise conv (DC=4) + bias + silu -> xcb bf16 ----------------
__global__ void conv_silu_kernel(const float* __restrict__ xz, const float* __restrict__ cW,
                                 const float* __restrict__ cb, u16* __restrict__ xcb){
  int idx = blockIdx.x*256 + threadIdx.x;   // over TOK*DI/4
  if (idx >= TOK_*DI_/4) return;
  int c4 = idx & (DI_/4 - 1); int t = idx >> 8;
  int l = t & (NP_-1);
  int c = c4*4;
  float4 acc = *(const float4*)&cb[c];
  float wa[4], wb[4], wc[4], wd[4];
  *(float4*)wa = *(const float4*)&cW[(c+0)*DC_];
  *(float4*)wb = *(const float4*)&cW[(c+1)*DC_];
  *(float4*)wc = *(const float4*)&cW[(c+2)*DC_];
  *(float4*)wd = *(const float4*)&cW[(c+3)*DC_];
  const float* base = xz + (size_t)t*(2*DI_) + c;
  #pragma unroll
  for (int k = 0; k < DC_; k++){
    if (l - 3 + k >= 0){
      float4 xv = *(const float4*)(base + (k-3)*(2*DI_));
      acc.x += xv.x*wa[k];
      acc.y += xv.y*wb[k];
      acc.z += xv.z*wc[k];
      acc.w += xv.w*wd[k];
    }
  }
  ushort4 pb = { f2bf(silu_f(acc.x)), f2bf(silu_f(acc.y)),
                 f2bf(silu_f(acc.z)), f2bf(silu_f(acc.w)) };
  *(ushort4*)&xcb[(size_t)t*DI_ + c] = pb;
}

// ---------------- delta (+dbl partial sum), 16 t per block ----------------
// sums the 4 split-K partials; dx==0 also writes B/C cols (32..64) of dbl.
__global__ __launch_bounds__(256) void delta_kernel(const float* __restrict__ part,
    const float* __restrict__ wdtT, const float* __restrict__ bdt,
    float* __restrict__ dbl, float* __restrict__ delta){
  __shared__ float sdt[16][DTR_];
  int tid = threadIdx.x;
  int t0 = blockIdx.y*16;
  int dx = blockIdx.x;
  int d = dx*256 + tid;
  for (int i = tid; i < 16*32; i += 256){
    int t = i >> 5, r = i & 31;
    size_t o = (size_t)(t0 + t)*64 + r;
    sdt[t][r] = part[o] + part[(size_t)TOK_*64 + o]
              + part[(size_t)2*TOK_*64 + o] + part[(size_t)3*TOK_*64 + o];
  }
  if (dx == 0){
    for (int i = tid; i < 16*32; i += 256){
      int t = i >> 5, c = i & 31;
      size_t o = (size_t)(t0 + t)*64 + 32 + c;
      dbl[o] = part[o] + part[(size_t)TOK_*64 + o]
             + part[(size_t)2*TOK_*64 + o] + part[(size_t)3*TOK_*64 + o];
    }
  }
  float wv[DTR_];
  #pragma unroll
  for (int r = 0; r < DTR_; r++) wv[r] = wdtT[(size_t)r*DI_ + d];
  float bb = bdt[d];
  __syncthreads();
  #pragma unroll 4
  for (int t = 0; t < 16; t++){
    float acc = bb;
    #pragma unroll
    for (int r = 0; r < DTR_; r++) acc += sdt[t][r]*wv[r];
    delta[(size_t)(t0 + t)*DI_ + d] = softplus_f(acc);
  }
}

// ---------------- chunked selective scan, d-per-lane ----------------
__global__ __launch_bounds__(256) void scan_part_kernel(const float* __restrict__ delta,
    const u16* __restrict__ xcb, const float* __restrict__ dbl,
    const float* __restrict__ Alog, float* __restrict__ hend, float* __restrict__ aprod){
  __shared__ float sBC[CL_][32];
  int tid = threadIdx.x;
  int d = blockIdx.x*256 + tid;
  int bych = blockIdx.y;               // b*NCH + ch
  int b = bych >> 4, ch = bych & (NCH_-1);
  int base = b*NP_ + ch*CL_;
  for (int i = tid; i < CL_*32; i += 256){
    int t = i >> 5, c = i & 31;
    sBC[t][c] = dbl[(size_t)(base+t)*64 + 32 + c];
  }
  float A[NS_], h[NS_], pr[NS_];
  #pragma unroll
  for (int k = 0; k < NS_; k++){
    A[k] = -__expf(Alog[(size_t)d*NS_ + k]);
    h[k] = 0.f; pr[k] = 1.f;
  }
  __syncthreads();
  #pragma unroll
  for (int t = 0; t < CL_; t++){
    int row = base + t;
    float de = delta[(size_t)row*DI_ + d];
    float xv = bf2f(xcb[(size_t)row*DI_ + d]);
    float cde = de*xv;
    #pragma unroll
    for (int k = 0; k < NS_; k++){
      float a = __expf(de*A[k]);
      h[k] = a*h[k] + cde*sBC[t][k];
      pr[k] *= a;
    }
  }
  size_t o = ((size_t)bych*DI_ + d)*NS_;
  #pragma unroll
  for (int k = 0; k < NS_; k++){ hend[o+k] = h[k]; aprod[o+k] = pr[k]; }
}

__global__ __launch_bounds__(256) void scan_fix_kernel(const float* __restrict__ aprod,
    float* __restrict__ hend){
  int id = blockIdx.x*256 + threadIdx.x;  // over B*DI*NS = 131072
  int nd = id & (DI_*NS_ - 1);
  int b  = id >> 14;
  float h = 0.f;
  #pragma unroll
  for (int ch = 0; ch < NCH_; ch++){
    size_t idx = (size_t)(b*NCH_ + ch)*(DI_*NS_) + nd;
    float ap = aprod[idx];
    float he = hend[idx];
    hend[idx] = h;
    h = ap*h + he;
  }
}

__global__ __launch_bounds__(256) void scan_final_kernel(const float* __restrict__ delta,
    const u16* __restrict__ xcb, const float* __restrict__ dbl,
    const float* __restrict__ xz, const float* __restrict__ Dv,
    const float* __restrict__ Alog, const float* __restrict__ hin,
    u16* __restrict__ yb){
  __shared__ float sBC[CL_][32];
  int tid = threadIdx.x;
  int d = blockIdx.x*256 + tid;
  int bych = blockIdx.y;
  int b = bych >> 4, ch = bych & (NCH_-1);
  int base = b*NP_ + ch*CL_;
  for (int i = tid; i < CL_*32; i += 256){
    int t = i >> 5, c = i & 31;
    sBC[t][c] = dbl[(size_t)(base+t)*64 + 32 + c];
  }
  float A[NS_], h[NS_];
  size_t o = ((size_t)bych*DI_ + d)*NS_;
  #pragma unroll
  for (int k = 0; k < NS_; k++){
    A[k] = -__expf(Alog[(size_t)d*NS_ + k]);
    h[k] = hin[o + k];
  }
  float Dvd = Dv[d];
  __syncthreads();
  #pragma unroll
  for (int t = 0; t < CL_; t++){
    int row = base + t;
    float de = delta[(size_t)row*DI_ + d];
    float xv = bf2f(xcb[(size_t)row*DI_ + d]);
    float zz = xz[(size_t)row*(2*DI_) + DI_ + d];
    float cde = de*xv;
    float p = 0.f;
    #pragma unroll
    for (int k = 0; k < NS_; k++){
      float a = __expf(de*A[k]);
      h[k] = a*h[k] + cde*sBC[t][k];
      p += h[k]*sBC[t][16+k];
    }
    yb[(size_t)row*DI_ + d] = f2bf((p + xv*Dvd) * silu_f(zz));
  }
}

// ---------------- head GEMM1 as MFMA: C[128n][8m], split-K 512, in-kernel fp32->bf16 ----------------
__global__ __launch_bounds__(256) void head1_kernel(const float* __restrict__ hW1,
    const u16* __restrict__ ub, float* __restrict__ partial){
  __shared__ __align__(16) u16 As[128*64];
  __shared__ __align__(16) u16 Bs[16*64];
  int tid = threadIdx.x;
  int wave = __builtin_amdgcn_readfirstlane(tid>>6);
  int lane = tid & 63, quad = lane>>4, l16 = lane&15;
  int kc = blockIdx.x;              // 0..511, KLEN=256
  int arow = tid & 127, apair = tid >> 7;
  floatx4 acc[2] = {};
  for (int sc = 0; sc < 4; sc++){
    int k0 = kc*256 + sc*64;
    const float* ap = hW1 + (size_t)arow*KTOT_ + k0 + apair*32;
    #pragma unroll
    for (int s = 0; s < 4; s++){
      float4 f0 = *(const float4*)(ap + s*8);
      float4 f1 = *(const float4*)(ap + s*8 + 4);
      union { u16 h[8]; int4 v; } pk;
      pk.h[0]=f2bf(f0.x); pk.h[1]=f2bf(f0.y); pk.h[2]=f2bf(f0.z); pk.h[3]=f2bf(f0.w);
      pk.h[4]=f2bf(f1.x); pk.h[5]=f2bf(f1.y); pk.h[6]=f2bf(f1.z); pk.h[7]=f2bf(f1.w);
      int seg = apair*4 + s;
      *(int4*)&As[arow*64 + ((seg^(arow&7))*8)] = pk.v;
    }
    if (tid < 128){
      int brow = tid >> 3, bseg = tid & 7;
      int4 bv = {0,0,0,0};
      if (brow < 8) bv = *(const int4*)&ub[(size_t)brow*KTOT_ + k0 + bseg*8];
      *(int4*)&Bs[brow*64 + ((bseg^(brow&7))*8)] = bv;
    }
    __syncthreads();
    #pragma unroll
    for (int kh = 0; kh < 2; kh++){
      short8 bf = *(short8*)&Bs[l16*64 + (((kh*4+quad)^(l16&7))*8)];
      #pragma unroll
      for (int i = 0; i < 2; i++){
        int row = wave*32 + i*16 + l16;
        short8 af = *(short8*)&As[row*64 + (((kh*4+quad)^(row&7))*8)];
        acc[i] = __builtin_amdgcn_mfma_f32_16x16x32_bf16(af, bf, acc[i], 0, 0, 0);
      }
    }
    __syncthreads();
  }
  if (l16 < 8){
    #pragma unroll
    for (int i = 0; i < 2; i++)
      #pragma unroll
      for (int r = 0; r < 4; r++){
        int n = wave*32 + i*16 + quad*4 + r;
        partial[(size_t)kc*1024 + n*8 + l16] = acc[i][r];
      }
  }
}

// stage 1: pp2[8][1024] = sum of 64 kc-partials each
__global__ void head_comb1_kernel(const float* __restrict__ partial, float* __restrict__ pp2){
  int out = blockIdx.x*256 + threadIdx.x;   // 0..1023
  int g = blockIdx.y;                        // 0..7
  const float* p = partial + (size_t)g*64*1024 + out;
  float s = 0.f;
  #pragma unroll 8
  for (int j = 0; j < 64; j++) s += p[(size_t)j*1024];
  pp2[g*1024 + out] = s;
}

// stage 2: t1[m*128+n] = gelu(hb1[n] + sum_g pp2)
__global__ void head_comb2_kernel(const float* __restrict__ pp2,
    const float* __restrict__ hb1, float* __restrict__ t1){
  int out = blockIdx.x*256 + threadIdx.x;   // 0..1023
  int n = out >> 3, m = out & 7;
  float s = hb1[n];
  #pragma unroll
  for (int g = 0; g < 8; g++) s += pp2[g*1024 + out];
  float ge = 0.5f*s*(1.f + erff(s*0.70710678118f));
  t1[m*128 + n] = ge;
}

__global__ void head2_kernel(const float* __restrict__ t1, const float* __restrict__ hW2,
                             const float* __restrict__ hb2, float* __restrict__ out){
  int idx = blockIdx.x*128 + threadIdx.x;  // 8*96
  if (idx >= B_*PRED_) return;
  int m = idx / PRED_, q = idx % PRED_;
  float s = hb2[q];
  #pragma unroll 16
  for (int k = 0; k < 2*CD_; k++) s += t1[m*128 + k]*hW2[q*128 + k];
  out[idx] = s;
}

// ---------------- prep: vectorized bf16 conversions + transposes ----------------
__global__ __launch_bounds__(256) void prep_kernel(const float* __restrict__ W_dt,
    const float* __restrict__ W_x, const float* __restrict__ W_in,
    const float* __restrict__ W_out, const float* __restrict__ peW,
    float* __restrict__ wdtT, u16* __restrict__ wxB,
    u16* __restrict__ WinB, u16* __restrict__ WoutB, u16* __restrict__ peWb){
  int idx = blockIdx.x*256 + threadIdx.x;   // 1,048,576 threads
  {
    float4 v = ((const float4*)W_in)[idx];
    ushort4 o = { f2bf(v.x), f2bf(v.y), f2bf(v.z), f2bf(v.w) };
    ((ushort4*)WinB)[idx] = o;
  }
  if (idx < 524288){
    float4 v = ((const float4*)W_out)[idx];
    ushort4 o = { f2bf(v.x), f2bf(v.y), f2bf(v.z), f2bf(v.w) };
    ((ushort4*)WoutB)[idx] = o;
  }
  if (idx < NL_*64*DI_/4){   // wxB: straight bf16 copy of W_x (NT layout already)
    float4 v = ((const float4*)W_x)[idx];
    ushort4 o = { f2bf(v.x), f2bf(v.y), f2bf(v.z), f2bf(v.w) };
    ((ushort4*)wxB)[idx] = o;
  }
  if (idx < NL_*DTR_*DI_){
    int l = idx / (DTR_*DI_); int rem = idx % (DTR_*DI_);
    int r = rem / DI_; int d = rem % DI_;
    wdtT[idx] = W_dt[((size_t)l*DI_ + d)*DTR_ + r];
  }
  if (idx < 512*128){
    int d = idx >> 7, kk = idx & 127;
    peWb[idx] = (kk < 112) ? f2bf(peW[d*112 + kk]) : (u16)0;
  }
}

extern "C" void kernel_launch(void* const* d_in, const int* in_sizes, int n_in,
                              void* d_out, int out_size, void* d_ws, size_t ws_size,
                              hipStream_t stream) {
  const float* x      = (const float*)d_in[0];
  const float* in_g   = (const float*)d_in[1];
  const float* in_b   = (const float*)d_in[2];
  const float* pe_W   = (const float*)d_in[3];
  const float* pe_b   = (const float*)d_in[4];
  const float* ln_g   = (const float*)d_in[5];
  const float* ln_b   = (const float*)d_in[6];
  const float* W_in   = (const float*)d_in[7];
  const float* conv_W = (const float*)d_in[8];
  const float* conv_b = (const float*)d_in[9];
  const float* W_x    = (const float*)d_in[10];
  const float* W_dt   = (const float*)d_in[11];
  const float* b_dt   = (const float*)d_in[12];
  const float* A_log  = (const float*)d_in[13];
  const float* Dskip  = (const float*)d_in[14];
  const float* W_out  = (const float*)d_in[15];
  const float* fn_g   = (const float*)d_in[16];
  const float* fn_b   = (const float*)d_in[17];
  const float* hW1    = (const float*)d_in[18];
  const float* hb1    = (const float*)d_in[19];
  const float* hW2    = (const float*)d_in[20];
  const float* hb2    = (const float*)d_in[21];

  float* ws    = (float*)d_ws;
  float* h     = ws;                    // 1,048,576 f
  float* un    = h     + 1048576;       // 1,048,576 f (unused; kept for layout)
  float* xz    = un    + 1048576;       // 4,194,304 f
  float* xc    = xz    + 4194304;       // 2,097,152 f  (first half = xcb bf16)
  float* dblb  = xc    + 2097152;       //   131,072 f
  float* delta = dblb  + 131072;        // 2,097,152 f
  float* y     = delta + 2097152;       // 2,097,152 f  (overlays: xpb prologue, hend scan)
  float* wdtT  = y     + 2097152;       //   131,072 f
  u16*   wxB   = (u16*)(wdtT + 131072);         //   262,144 u16 (=131,072 f)
  float* bf_rgn= wdtT + 131072 + 131072;
  u16*   unb   = (u16*)bf_rgn;                  // 1,048,576 u16
  u16*   yb    = (u16*)(bf_rgn + 524288);       // 2,097,152 u16
  u16*   WinB  = (u16*)(bf_rgn + 524288 + 1048576);            // 4,194,304 u16
  u16*   WoutB = (u16*)(bf_rgn + 524288 + 1048576 + 2097152);  // 2,097,152 u16
  u16*   peWb  = (u16*)(bf_rgn + 524288 + 1048576 + 2097152 + 1048576); // 65,536 u16
  float* aprod = bf_rgn + 524288 + 1048576 + 2097152 + 1048576 + 32768; // 2,097,152 f
  // end ≈ 79.3 MB
  float* hend  = y;                     // [B*NCH][DI][NS]; becomes hin after pass B
  u16*   xcb   = (u16*)xc;              // bf16 xc [2048][1024] (alive through scan_final)
  u16*   xpb   = (u16*)y;               // prologue-only: bf16 patches [2048][128]
  float* dblpart = aprod;               // [4][2048][64] = 524,288 f; consumed before scan_part
  float* partial = xz;                  // epilogue-only (512*1024 = 524,288 f)
  float* pp2     = xz + 524288;         // 8,192 f
  float* t1      = xz + 532480;         // 1,024 f

  prep_kernel<<<4096, 256, 0, stream>>>(W_dt, W_x, W_in, W_out, pe_W,
                                        wdtT, wxB, WinB, WoutB, peWb);
  ln7_kernel<<<(B_*SEQ_+255)/256, 256, 0, stream>>>(x, in_g, in_b, xpb);
  // patch-embed as bf16 GEMM: h[2048][512] = xpb[2048][128] @ peWb[512][128]^T + pe_b
  gemm_bf16<64,128,false,true><<<dim3(DM_/128, TOK_/64), 256, 0, stream>>>(
      xpb, peWb, h, pe_b, 128, 128, 128, DM_);

  for (int l = 0; l < NL_; l++){
    ln512_kernel<<<TOK_/4, 256, 0, stream>>>(h, ln_g + l*DM_, ln_b + l*DM_, unb);
    gemm_bf16<64,128,false,false><<<dim3(2*DI_/128, TOK_/64), 256, 0, stream>>>(
        unb, WinB + (size_t)l*2*DI_*DM_, xz, nullptr, DM_, DM_, DM_, 2*DI_);
    conv_silu_kernel<<<(TOK_*DI_/4)/256, 256, 0, stream>>>(
        xz, conv_W + (size_t)l*DI_*DC_, conv_b + (size_t)l*DI_, xcb);
    // dbl partials: [4][2048][64] = xcb @ W_x^T split-K
    dblpart_kernel<<<dim3(TOK_/64, 4), 256, 0, stream>>>(
        xcb, wxB + (size_t)l*64*DI_, dblpart);
    delta_kernel<<<dim3(DI_/256, TOK_/16), 256, 0, stream>>>(
        dblpart, wdtT + (size_t)l*DTR_*DI_, b_dt + (size_t)l*DI_, dblb, delta);
    scan_part_kernel<<<dim3(DI_/256, B_*NCH_), 256, 0, stream>>>(
        delta, xcb, dblb, A_log + (size_t)l*DI_*NS_, hend, aprod);
    scan_fix_kernel<<<(B_*DI_*NS_)/256, 256, 0, stream>>>(aprod, hend);
    scan_final_kernel<<<dim3(DI_/256, B_*NCH_), 256, 0, stream>>>(
        delta, xcb, dblb, xz, Dskip + (size_t)l*DI_, A_log + (size_t)l*DI_*NS_, hend, yb);
    gemm_bf16<64,64,true,false><<<dim3(DM_/64, TOK_/64), 256, 0, stream>>>(
        yb, WoutB + (size_t)l*DM_*DI_, h, nullptr, DI_, DI_, DI_, DM_);
  }

  ln512_kernel<<<TOK_/4, 256, 0, stream>>>(h, fn_g, fn_b, unb);
  head1_kernel<<<512, 256, 0, stream>>>(hW1, unb, partial);
  head_comb1_kernel<<<dim3(4, 8), 256, 0, stream>>>(partial, pp2);
  head_comb2_kernel<<<4, 256, 0, stream>>>(pp2, hb1, t1);
  head2_kernel<<<6, 128, 0, stream>>>(t1, hW2, hb2, (float*)d_out);
}